// Round 1
// baseline (89.877 us; speedup 1.0000x reference)
//
#include <hip/hip_runtime.h>

#define N_SAMPLES 65536
#define CHUNKS_PER_BATCH 64   // 64 blocks x 256 thr x 4 samples = 65536

// out[b][n] = sin(2*pi*phi) * fm * window * sin(pi*am*t)
//   phi    = F0/(fm*ln2) * (exp2(fm*t) - 1)
//   t      = (n - 32768)/44100          (N//2 offset)
//   wsupp  = n - 32767.5                (linspace offset -- differs from t!)
//   window = exp(-(wsupp * fm/(4410*sqrt2))^2)
//   am_hz  = exp2(2*theta_am + 2)   [4..16]
//   fm_hz  = exp2(3*theta_fm - 1)   [0.5..4]
__global__ __launch_bounds__(256) void chirplet_synth_kernel(
    const float* __restrict__ theta_am,
    const float* __restrict__ theta_fm,
    float* __restrict__ out)
{
    const int bid   = blockIdx.x;
    const int b     = bid >> 6;            // batch index (uniform per block)
    const int chunk = bid & (CHUNKS_PER_BATCH - 1);
    const int n0    = (chunk << 10) + (threadIdx.x << 2);

    // per-batch constants (scalarized by compiler: b is block-uniform)
    const float ta = theta_am[b];
    const float tf = theta_fm[b];
    const float am = exp2f(ta * 2.0f + 2.0f);
    const float fm = exp2f(tf * 3.0f - 1.0f);
    const float c        = 440.0f / (fm * 0.69314718055994531f); // F0/(fm*ln2)
    const float inv_den  = fm * (1.0f / (4410.0f * 1.41421356237309505f));
    const float am_half  = am * 0.5f;                  // revolutions coeff for modulator
    const float inv_sr   = 1.0f / 44100.0f;
    const float LOG2E    = 1.44269504088896340f;

    float4 r;
    float res[4];
#pragma unroll
    for (int i = 0; i < 4; ++i) {
        const float nf = (float)(n0 + i);
        const float t  = (nf - 32768.0f) * inv_sr;
        const float ws = nf - 32767.5f;

        // carrier: sin(2*pi*phi) -> v_sin with revolutions input, fract-reduced
        const float e    = exp2f(fm * t);              // v_exp_f32
        const float phi  = c * (e - 1.0f);             // revolutions
        const float carr = __builtin_amdgcn_sinf(__builtin_amdgcn_fractf(phi));

        // modulator: sin(2*pi * (am/2 * t))
        const float mrev = am_half * t;
        const float modu = __builtin_amdgcn_sinf(__builtin_amdgcn_fractf(mrev));

        // Gaussian window
        const float wv  = ws * inv_den;
        const float win = exp2f(-(wv * wv) * LOG2E);   // v_exp_f32

        res[i] = carr * fm * win * modu;
    }
    r.x = res[0]; r.y = res[1]; r.z = res[2]; r.w = res[3];
    *reinterpret_cast<float4*>(&out[(size_t)b * N_SAMPLES + n0]) = r;
}

extern "C" void kernel_launch(void* const* d_in, const int* in_sizes, int n_in,
                              void* d_out, int out_size, void* d_ws, size_t ws_size,
                              hipStream_t stream) {
    const float* theta_am = (const float*)d_in[0];
    const float* theta_fm = (const float*)d_in[1];
    // d_in[2] (seed) is unused by the reference's output
    float* out = (float*)d_out;

    const int B = in_sizes[0];                 // 256
    dim3 grid(B * CHUNKS_PER_BATCH), block(256);
    chirplet_synth_kernel<<<grid, block, 0, stream>>>(theta_am, theta_fm, out);
}

// Round 4
// 88.039 us; speedup vs baseline: 1.0209x; 1.0209x over previous
//
#include <hip/hip_runtime.h>

#define NS 65536
#define CHUNK_LOG 4          // 16 chunks per batch row
#define CHUNK_SAMPLES 4096   // 256 threads * 16 samples

typedef float f32x4 __attribute__((ext_vector_type(4)));  // native vec: OK for nontemporal builtin

// out[b][n] = sin(2*pi*phi) * fm * window * sin(pi*am*t)
//   phi    = 440/(fm*ln2) * (exp2(fm*t) - 1),  t = (n - 32768)/44100
//   wsupp  = n - 32767.5 (linspace offset, differs from t!)
//   window = exp(-(wsupp * fm/(4410*sqrt2))^2)
//   am_hz = exp2(2*theta_am + 2), fm_hz = exp2(3*theta_fm - 1)
// Zero-skip: window <= 1.4e-11 when |wsupp| >= 5*6236.68/fm -> store zeros,
// skip all transcendentals (error ~5e-11 vs threshold 4.7e-2).
__global__ __launch_bounds__(256) void chirplet_synth_kernel(
    const float* __restrict__ theta_am,
    const float* __restrict__ theta_fm,
    float* __restrict__ out)
{
    const int bid   = blockIdx.x;
    const int b     = bid >> CHUNK_LOG;              // batch (block-uniform)
    const int chunk = bid & ((1 << CHUNK_LOG) - 1);
    const int base  = chunk * CHUNK_SAMPLES;

    const float tf = theta_fm[b];
    const float fm = exp2f(tf * 3.0f - 1.0f);

    float* outp = out + (size_t)b * NS + base + (threadIdx.x << 2);

    // ---- block-uniform zero-skip ----
    const float T  = 31182.0f / fm;                  // |ws| beyond => win < 1.4e-11
    const float lo = (float)base - 32767.5f;
    const float hi = (float)(base + CHUNK_SAMPLES - 1) - 32767.5f;
    if (lo > T || hi < -T) {
        const f32x4 z = {0.f, 0.f, 0.f, 0.f};
#pragma unroll
        for (int j = 0; j < 4; ++j)
            __builtin_nontemporal_store(z, reinterpret_cast<f32x4*>(outp + (j << 10)));
        return;
    }

    // ---- per-thread constants (amortized over 16 samples) ----
    const float ta      = theta_am[b];
    const float am      = exp2f(ta * 2.0f + 2.0f);
    const float c       = 440.0f / (fm * 0.69314718055994531f);   // F0/(fm*ln2)
    const float inv_den = fm * (1.0f / 6236.68503f);              // fm/(4410*sqrt2)
    const float am_half = am * 0.5f;
    const float inv_sr  = 1.0f / 44100.0f;
    const float LOG2E   = 1.44269504088896340f;

#pragma unroll
    for (int j = 0; j < 4; ++j) {
        const int n0 = base + (threadIdx.x << 2) + (j << 10);
        float res[4];
#pragma unroll
        for (int i = 0; i < 4; ++i) {
            const float nf = (float)(n0 + i);
            const float t  = (nf - 32768.0f) * inv_sr;
            const float ws = nf - 32767.5f;

            const float e    = exp2f(fm * t);                       // v_exp_f32
            const float phi  = c * (e - 1.0f);                      // revolutions
            const float carr = __builtin_amdgcn_sinf(__builtin_amdgcn_fractf(phi));
            const float modu = __builtin_amdgcn_sinf(__builtin_amdgcn_fractf(am_half * t));

            const float wv  = ws * inv_den;
            const float win = exp2f(-(wv * wv) * LOG2E);            // v_exp_f32

            res[i] = carr * fm * win * modu;
        }
        f32x4 r = {res[0], res[1], res[2], res[3]};
        __builtin_nontemporal_store(r, reinterpret_cast<f32x4*>(outp + (j << 10)));
    }
}

extern "C" void kernel_launch(void* const* d_in, const int* in_sizes, int n_in,
                              void* d_out, int out_size, void* d_ws, size_t ws_size,
                              hipStream_t stream) {
    const float* theta_am = (const float*)d_in[0];
    const float* theta_fm = (const float*)d_in[1];
    // d_in[2] (seed) is unused by the reference
    float* out = (float*)d_out;

    const int B = in_sizes[0];                       // 256
    dim3 grid(B << CHUNK_LOG), block(256);
    chirplet_synth_kernel<<<grid, block, 0, stream>>>(theta_am, theta_fm, out);
}

// Round 6
// 81.886 us; speedup vs baseline: 1.0976x; 1.0751x over previous
//
#include <hip/hip_runtime.h>

#define NS 65536
#define CHUNK_LOG 3                   // 8 chunks per batch row
#define GROUPS 8                      // per thread: 8 groups of 4 consecutive samples
#define CHUNK_SAMPLES (GROUPS * 1024) // 256 thr * 4 * GROUPS = 8192

typedef float f32x4 __attribute__((ext_vector_type(4)));

// out[b][n] = sin(2*pi*phi) * fm * window * sin(pi*am*t)
//   phi    = 440/(fm*ln2) * (exp2(fm*t) - 1),  t = (n - 32768)/44100
//   wsupp  = n - 32767.5 (linspace offset, differs from t!)
//   window = exp(-(wsupp * fm/(4410*sqrt2))^2) = 2^(-k2*ws^2)
//   am_hz = exp2(2*theta_am + 2), fm_hz = exp2(3*theta_fm - 1)
//
// Trans budget: 7 trans per ALIVE 4-sample group (e-anchor, window-anchor, v1,
// 4 carrier sins); modulator entirely on a rotation recurrence. Each group is
// RE-ANCHORED with fresh exp2 (R5 bug: thread-global multiplicative window
// chain hit fp32 underflow at |ws0|~16k and stayed 0 into the alive region).
// Per-group zero-skip when 2^q < 2^-36.5 (window < 1e-11).
__global__ __launch_bounds__(256) void chirplet_synth_kernel(
    const float* __restrict__ theta_am,
    const float* __restrict__ theta_fm,
    float* __restrict__ out)
{
    const int bid   = blockIdx.x;
    const int b     = bid >> CHUNK_LOG;               // batch (block-uniform)
    const int chunk = bid & ((1 << CHUNK_LOG) - 1);
    const int base  = chunk * CHUNK_SAMPLES;
    const int tid4  = threadIdx.x << 2;

    const float tf = theta_fm[b];
    const float fm = exp2f(tf * 3.0f - 1.0f);

    float* outp = out + (size_t)b * NS + base + tid4;

    // ---- whole-chunk zero-skip (block-uniform) ----
    const float T = 31182.0f / fm;                    // 2^(-36) window cutoff
    {
        const float lo = (float)base - 32767.5f;
        const float hi = (float)(base + CHUNK_SAMPLES - 1) - 32767.5f;
        if (lo > T || hi < -T) {
            const f32x4 z = {0.f, 0.f, 0.f, 0.f};
#pragma unroll
            for (int gi = 0; gi < GROUPS; ++gi)
                __builtin_nontemporal_store(z, reinterpret_cast<f32x4*>(outp + (gi << 10)));
            return;
        }
    }

    const float ta = theta_am[b];
    const float am = exp2f(ta * 2.0f + 2.0f);

    const float inv_sr = 1.0f / 44100.0f;
    const float n0f = (float)(base + tid4);
    const float t0  = (n0f - 32768.0f) * inv_sr;
    const float ws0 = n0f - 32767.5f;

    // carrier constants
    const float c  = 440.0f / (fm * 0.69314718055994531f);
    const float r1 = exp2f(fm * inv_sr);              // per-sample ratio of e

    // window constants: window = 2^(-k2*ws^2)
    const float invd = fm * (1.0f / 6236.68503f);
    const float k2   = invd * invd * 1.44269504f;
    const float P1   = exp2f(-2.0f * k2);             // ratio-of-ratios, +1 step

    // modulator rotation recurrence (state at current group's first sample)
    const float m1  = am * (0.5f * inv_sr);           // rev per sample
    const float th0 = am * 0.5f * t0;
    float s  = __builtin_amdgcn_sinf(__builtin_amdgcn_fractf(th0));
    float cc = __builtin_amdgcn_cosf(__builtin_amdgcn_fractf(th0));
    const float sd1 = __builtin_amdgcn_sinf(m1);      // +1 sample rotation
    const float cd1 = __builtin_amdgcn_cosf(m1);
    const float mG  = m1 * 1024.0f;                   // group-to-group rotation
    const float sdG = __builtin_amdgcn_sinf(__builtin_amdgcn_fractf(mG));
    const float cdG = __builtin_amdgcn_cosf(__builtin_amdgcn_fractf(mG));

#pragma unroll
    for (int gi = 0; gi < GROUPS; ++gi) {
        const float ws_g = ws0 + (float)(gi << 10);
        const float q    = -k2 * ws_g * ws_g;         // log2(window) at group start

        if (q > -36.5f) {                             // group alive
            const float t_g = (n0f + (float)(gi << 10) - 32768.0f) * inv_sr;
            float e  = exp2f(fm * t_g);               // fresh anchor (no drift/underflow)
            float g  = fm * exp2f(q);
            float v1 = exp2f(-k2 * (2.0f * ws_g + 1.0f));
            float ls = s, lc = cc;

            float res[4];
#pragma unroll
            for (int i = 0; i < 4; ++i) {
                const float phi  = c * (e - 1.0f);    // matches ref rounding order
                const float carr = __builtin_amdgcn_sinf(__builtin_amdgcn_fractf(phi));
                res[i] = carr * g * ls;
                if (i < 3) {
                    e *= r1;
                    g *= v1;  v1 *= P1;
                    const float ns = __builtin_fmaf(ls, cd1,  lc * sd1);
                    const float nc = __builtin_fmaf(lc, cd1, -ls * sd1);
                    ls = ns; lc = nc;
                }
            }
            f32x4 r = {res[0], res[1], res[2], res[3]};
            __builtin_nontemporal_store(r, reinterpret_cast<f32x4*>(outp + (gi << 10)));
        } else {                                      // group dead -> zeros
            const f32x4 z = {0.f, 0.f, 0.f, 0.f};
            __builtin_nontemporal_store(z, reinterpret_cast<f32x4*>(outp + (gi << 10)));
        }

        // advance modulator state by +1024 samples (group start -> group start)
        const float ns = __builtin_fmaf(s, cdG,  cc * sdG);
        const float nc = __builtin_fmaf(cc, cdG, -s * sdG);
        s = ns; cc = nc;
    }
}

extern "C" void kernel_launch(void* const* d_in, const int* in_sizes, int n_in,
                              void* d_out, int out_size, void* d_ws, size_t ws_size,
                              hipStream_t stream) {
    const float* theta_am = (const float*)d_in[0];
    const float* theta_fm = (const float*)d_in[1];
    // d_in[2] (seed) is unused by the reference
    float* out = (float*)d_out;

    const int B = in_sizes[0];                        // 256
    dim3 grid(B << CHUNK_LOG), block(256);            // 2048 blocks
    chirplet_synth_kernel<<<grid, block, 0, stream>>>(theta_am, theta_fm, out);
}

// Round 7
// 79.571 us; speedup vs baseline: 1.1295x; 1.0291x over previous
//
#include <hip/hip_runtime.h>

#define NS 65536

typedef float f32x4 __attribute__((ext_vector_type(4)));

// out[b][n] = sin(2*pi*phi) * fm * window * sin(pi*am*t)
//   phi    = 440/(fm*ln2) * (exp2(fm*t) - 1),  t = (n - 32768)/44100
//   wsupp  = n - 32767.5 (linspace offset, differs from t!)
//   window = 2^(-k2*wsupp^2),  k2 = (fm/6236.685)^2 * log2(e)
//   am_hz = exp2(2*theta_am+2), fm_hz = exp2(3*theta_fm-1)
//
// Load-balance: block c of each batch handles 1024-sample groups {c, c+8,
// ..., c+56} -- every block spans the full row, so alive/dead work is
// IDENTICAL across blocks (R6 theory: whole-dead blocks caused CU imbalance,
// kernel time = slowest CU).
// Trans budget per alive group: 1 exp2 (window anchor, fresh per R5 lesson:
// never chain through an underflow region) + 4 carrier sins. e = 2^(fm*t)
// (range [0.13,7.8], safe) and v1 (~1.0) are chained across the 8192-sample
// group stride; modulator is a rotation recurrence. Chain drift => <~1e-3
// output error (cph*fm = 635 independent of fm); threshold 4.7e-2.
__global__ __launch_bounds__(256) void chirplet_synth_kernel(
    const float* __restrict__ theta_am,
    const float* __restrict__ theta_fm,
    float* __restrict__ out)
{
    const int bid  = blockIdx.x;
    const int b    = bid >> 3;                 // batch (block-uniform)
    const int c    = bid & 7;                  // group phase 0..7
    const int tid4 = threadIdx.x << 2;

    const float tf = theta_fm[b];
    const float ta = theta_am[b];
    const float fm = exp2f(tf * 3.0f - 1.0f);
    const float am = exp2f(ta * 2.0f + 2.0f);

    const float inv_sr = 1.0f / 44100.0f;
    const float cph = 440.0f / (fm * 0.69314718055994531f);
    const float r1  = exp2f(fm * inv_sr);             // e ratio, +1 sample
    const float rG  = exp2f(fm * (8192.0f * inv_sr)); // e ratio, +8192 samples

    const float invd = fm * (1.0f / 6236.68503f);
    const float k2   = invd * invd * 1.44269504f;
    const float P1   = exp2f(-2.0f * k2);             // v1 ratio, +1 sample
    const float PG   = exp2f(-16384.0f * k2);         // v1 ratio, +8192 samples

    // modulator rotation constants (revolutions)
    const float m1  = am * (0.5f * inv_sr);
    const float sd1 = __builtin_amdgcn_sinf(m1);
    const float cd1 = __builtin_amdgcn_cosf(m1);
    const float mG  = __builtin_amdgcn_fractf(m1 * 8192.0f);
    const float sdG = __builtin_amdgcn_sinf(mG);
    const float cdG = __builtin_amdgcn_cosf(mG);

    // thread anchor at its first group (gi = 0)
    const int   n0  = (c << 10) + tid4;
    const float nf0 = (float)n0;
    const float t0  = (nf0 - 32768.0f) * inv_sr;
    const float ws0 = nf0 - 32767.5f;

    float e  = exp2f(fm * t0);                         // 2^(fm*t), safe range
    float vv = exp2f(-k2 * (2.0f * ws0 + 1.0f));       // ~1.0 always, safe
    const float th0 = __builtin_amdgcn_fractf(am * 0.5f * t0);
    float s  = __builtin_amdgcn_sinf(th0);
    float cn = __builtin_amdgcn_cosf(th0);

    float* outp = out + (size_t)b * NS + n0;
    const f32x4 z = {0.f, 0.f, 0.f, 0.f};

#pragma unroll
    for (int gi = 0; gi < 8; ++gi) {
        const float ws = ws0 + (float)(gi << 13);
        const float q  = -k2 * ws * ws;                // log2(window)
        float* o = outp + (gi << 13);

        if (q > -36.5f) {                              // group alive
            float le = e, lv = vv, ls = s, lc = cn;
            float g  = fm * exp2f(q);                  // fresh window anchor
            float res[4];
#pragma unroll
            for (int i = 0; i < 4; ++i) {
                const float phi  = __builtin_fmaf(cph, le, -cph);   // cph*(e-1)
                const float carr = __builtin_amdgcn_sinf(__builtin_amdgcn_fractf(phi));
                res[i] = carr * g * ls;
                if (i < 3) {
                    le *= r1;
                    g  *= lv;  lv *= P1;
                    const float ns2 = __builtin_fmaf(ls, cd1,  lc * sd1);
                    const float nc2 = __builtin_fmaf(lc, cd1, -ls * sd1);
                    ls = ns2; lc = nc2;
                }
            }
            f32x4 r = {res[0], res[1], res[2], res[3]};
            __builtin_nontemporal_store(r, reinterpret_cast<f32x4*>(o));
        } else {                                       // group dead -> zeros
            __builtin_nontemporal_store(z, reinterpret_cast<f32x4*>(o));
        }

        // advance chains by +8192 samples (uniform work, alive or dead)
        e  *= rG;
        vv *= PG;
        const float ns2 = __builtin_fmaf(s, cdG,  cn * sdG);
        const float nc2 = __builtin_fmaf(cn, cdG, -s * sdG);
        s = ns2; cn = nc2;
    }
}

extern "C" void kernel_launch(void* const* d_in, const int* in_sizes, int n_in,
                              void* d_out, int out_size, void* d_ws, size_t ws_size,
                              hipStream_t stream) {
    const float* theta_am = (const float*)d_in[0];
    const float* theta_fm = (const float*)d_in[1];
    // d_in[2] (seed) is unused by the reference
    float* out = (float*)d_out;

    const int B = in_sizes[0];                         // 256
    dim3 grid(B << 3), block(256);                     // 2048 blocks
    chirplet_synth_kernel<<<grid, block, 0, stream>>>(theta_am, theta_fm, out);
}

// Round 8
// 79.174 us; speedup vs baseline: 1.1352x; 1.0050x over previous
//
#include <hip/hip_runtime.h>

#define NS 65536

typedef float f32x4 __attribute__((ext_vector_type(4)));

// out[b][n] = sin(2*pi*phi) * fm * window * sin(pi*am*t)
//   phi    = 440/(fm*ln2) * (exp2(fm*t) - 1),  t = (n - 32768)/44100
//   wsupp  = n - 32767.5 (linspace offset, differs from t!)
//   window = 2^(-k2*wsupp^2),  k2 = (fm/6236.685)^2 * log2(e)
//   am_hz = exp2(2*theta_am+2), fm_hz = exp2(3*theta_fm-1)
//
// R7->R8 single change: plain (cacheable) stores instead of nontemporal.
// Theory: nt bypasses LLC -> synchronous HBM write path was the kernel's
// critical path; plain full-line writes retire into the 256MB Infinity
// Cache (64MB output fits) and drain async after kernel end.
__global__ __launch_bounds__(256) void chirplet_synth_kernel(
    const float* __restrict__ theta_am,
    const float* __restrict__ theta_fm,
    float* __restrict__ out)
{
    const int bid  = blockIdx.x;
    const int b    = bid >> 3;                 // batch (block-uniform)
    const int c    = bid & 7;                  // group phase 0..7
    const int tid4 = threadIdx.x << 2;

    const float tf = theta_fm[b];
    const float ta = theta_am[b];
    const float fm = exp2f(tf * 3.0f - 1.0f);
    const float am = exp2f(ta * 2.0f + 2.0f);

    const float inv_sr = 1.0f / 44100.0f;
    const float cph = 440.0f / (fm * 0.69314718055994531f);
    const float r1  = exp2f(fm * inv_sr);             // e ratio, +1 sample
    const float rG  = exp2f(fm * (8192.0f * inv_sr)); // e ratio, +8192 samples

    const float invd = fm * (1.0f / 6236.68503f);
    const float k2   = invd * invd * 1.44269504f;
    const float P1   = exp2f(-2.0f * k2);             // v1 ratio, +1 sample
    const float PG   = exp2f(-16384.0f * k2);         // v1 ratio, +8192 samples

    // modulator rotation constants (revolutions)
    const float m1  = am * (0.5f * inv_sr);
    const float sd1 = __builtin_amdgcn_sinf(m1);
    const float cd1 = __builtin_amdgcn_cosf(m1);
    const float mG  = __builtin_amdgcn_fractf(m1 * 8192.0f);
    const float sdG = __builtin_amdgcn_sinf(mG);
    const float cdG = __builtin_amdgcn_cosf(mG);

    // thread anchor at its first group (gi = 0)
    const int   n0  = (c << 10) + tid4;
    const float nf0 = (float)n0;
    const float t0  = (nf0 - 32768.0f) * inv_sr;
    const float ws0 = nf0 - 32767.5f;

    float e  = exp2f(fm * t0);                         // 2^(fm*t), safe range
    float vv = exp2f(-k2 * (2.0f * ws0 + 1.0f));       // ~1.0 always, safe
    const float th0 = __builtin_amdgcn_fractf(am * 0.5f * t0);
    float s  = __builtin_amdgcn_sinf(th0);
    float cn = __builtin_amdgcn_cosf(th0);

    float* outp = out + (size_t)b * NS + n0;
    const f32x4 z = {0.f, 0.f, 0.f, 0.f};

#pragma unroll
    for (int gi = 0; gi < 8; ++gi) {
        const float ws = ws0 + (float)(gi << 13);
        const float q  = -k2 * ws * ws;                // log2(window)
        float* o = outp + (gi << 13);

        if (q > -36.5f) {                              // group alive
            float le = e, lv = vv, ls = s, lc = cn;
            float g  = fm * exp2f(q);                  // fresh window anchor
            float res[4];
#pragma unroll
            for (int i = 0; i < 4; ++i) {
                const float phi  = __builtin_fmaf(cph, le, -cph);   // cph*(e-1)
                const float carr = __builtin_amdgcn_sinf(__builtin_amdgcn_fractf(phi));
                res[i] = carr * g * ls;
                if (i < 3) {
                    le *= r1;
                    g  *= lv;  lv *= P1;
                    const float ns2 = __builtin_fmaf(ls, cd1,  lc * sd1);
                    const float nc2 = __builtin_fmaf(lc, cd1, -ls * sd1);
                    ls = ns2; lc = nc2;
                }
            }
            f32x4 r = {res[0], res[1], res[2], res[3]};
            *reinterpret_cast<f32x4*>(o) = r;          // plain cacheable store
        } else {                                       // group dead -> zeros
            *reinterpret_cast<f32x4*>(o) = z;          // plain cacheable store
        }

        // advance chains by +8192 samples (uniform work, alive or dead)
        e  *= rG;
        vv *= PG;
        const float ns2 = __builtin_fmaf(s, cdG,  cn * sdG);
        const float nc2 = __builtin_fmaf(cn, cdG, -s * sdG);
        s = ns2; cn = nc2;
    }
}

extern "C" void kernel_launch(void* const* d_in, const int* in_sizes, int n_in,
                              void* d_out, int out_size, void* d_ws, size_t ws_size,
                              hipStream_t stream) {
    const float* theta_am = (const float*)d_in[0];
    const float* theta_fm = (const float*)d_in[1];
    // d_in[2] (seed) is unused by the reference
    float* out = (float*)d_out;

    const int B = in_sizes[0];                         // 256
    dim3 grid(B << 3), block(256);                     // 2048 blocks
    chirplet_synth_kernel<<<grid, block, 0, stream>>>(theta_am, theta_fm, out);
}